// Round 3
// baseline (8706.734 us; speedup 1.0000x reference)
//
#include <hip/hip_runtime.h>
#include <math.h>

#define T_STEPS 512
#define BATCH   256
#define DFEAT   128
#define DIN     257
#define DINP    288   // 257 padded to multiple of 32 (zeros)
#define HID     1024
#define G3      3072
#define OUTD    128

#define W_STRIDE 1032            // LDS row stride (shorts) for W_hh slice: 1024 + 8 pad
#define BUF_F32  13056           // 48 gate-blocks * 272 (16*17) f32
#define LDS_BYTES (BUF_F32 * 4 + 48 * W_STRIDE * 2)   // 52224 + 99072 = 151296

typedef __bf16 bf16x8 __attribute__((ext_vector_type(8)));
typedef float  f32x4  __attribute__((ext_vector_type(4)));

__device__ __forceinline__ unsigned short f2bf(float f) {
    unsigned int u = __float_as_uint(f);
    u += 0x7FFF + ((u >> 16) & 1);   // round-to-nearest-even
    return (unsigned short)(u >> 16);
}

// Build xt[t][b][c] (bf16, zero-padded to DINP) from x[b][t][d], mask[b][t][d], ti[b][t]
__global__ void build_xt(const float* __restrict__ x, const float* __restrict__ mask,
                         const float* __restrict__ ti, unsigned short* __restrict__ xt) {
    const int N = T_STEPS * BATCH * DINP;
    for (int idx = blockIdx.x * blockDim.x + threadIdx.x; idx < N;
         idx += gridDim.x * blockDim.x) {
        int c   = idx % DINP;
        int rem = idx / DINP;
        int b   = rem % BATCH;
        int t   = rem / BATCH;
        float v;
        if (c < DFEAT)            v = x[(b * T_STEPS + t) * DFEAT + c];
        else if (c < 2 * DFEAT)   v = mask[(b * T_STEPS + t) * DFEAT + (c - DFEAT)];
        else if (c == 2 * DFEAT)  v = ti[b * T_STEPS + t];
        else                      v = 0.f;
        xt[idx] = f2bf(v);
    }
}

// Persistent GRU: 256 blocks (1/CU, LDS-forced), block = (unit-tile ut, batch-group g).
// Waves K-split chunks c%4==w; W_hh slice LDS-resident all 512 steps; W_ih frags in regs.
// Cross-step sync: monotone flag counters per (group, t), device-scope atomics.
__global__ __launch_bounds__(256, 1) void gru_persist(
    const unsigned short* __restrict__ xt,
    const float* __restrict__ W_ih, const float* __restrict__ W_hh,
    const float* __restrict__ b_ih, const float* __restrict__ b_hh,
    unsigned short* hb0, unsigned short* hb1,
    float* __restrict__ hF, unsigned int* flags)
{
    extern __shared__ char smem[];
    float* buf = (float*)smem;                                   // 52224 B
    unsigned short* wlds = (unsigned short*)(smem + BUF_F32 * 4); // 48 x 1032 shorts

    const int tid = threadIdx.x;
    const int w   = tid >> 6;          // wave 0..3
    const int ln  = tid & 15;          // unit lane / A row lane
    const int q   = (tid & 63) >> 4;   // quad
    const int g   = blockIdx.x >> 6;   // batch group 0..3
    const int ut  = blockIdx.x & 63;   // unit tile 0..63
    const int u0  = ut * 16;
    const int bb  = g * 64;

    // ---- load W_hh slice into LDS (f32 -> bf16), rows = gate*16 + u ----
    for (int i = tid; i < 48 * 512; i += 256) {
        int row = i >> 9;                 // 0..47
        int c2  = (i & 511) * 2;          // 0..1022 step 2
        int grow = (row >> 4) * HID + u0 + (row & 15);
        const float* src = W_hh + (size_t)grow * HID + c2;
        unsigned int lo = f2bf(src[0]), hi = f2bf(src[1]);
        *(unsigned int*)(&wlds[row * W_STRIDE + c2]) = lo | (hi << 16);
    }

    // ---- W_ih fragments into registers: wave w owns x-chunks {w, w+4, w+8(<9)} ----
    bf16x8 xw[3][3];   // [chunk][gate r,z,n]
    const int nxc = (w == 0) ? 3 : 2;
    #pragma unroll
    for (int xi = 0; xi < 3; xi++) {
        int cx = w + xi * 4;
        #pragma unroll
        for (int G = 0; G < 3; G++) {
            unsigned short tmp[8];
            #pragma unroll
            for (int j = 0; j < 8; j++) {
                int col = cx * 32 + q * 8 + j;
                float f = (cx < 9 && col < DIN)
                    ? W_ih[(size_t)(G * HID + u0 + ln) * DIN + col] : 0.f;
                tmp[j] = f2bf(f);
            }
            xw[xi][G] = *(bf16x8*)tmp;
        }
    }

    // ---- biases (per lane unit), fp32 master h in regs ----
    const int gu = u0 + ln;
    const float bR  = b_ih[gu]            + b_hh[gu];
    const float bZ  = b_ih[HID + gu]      + b_hh[HID + gu];
    const float bIN = b_ih[2 * HID + gu];
    const float bHN = b_hh[2 * HID + gu];
    float hreg[4] = {0.f, 0.f, 0.f, 0.f};

    __syncthreads();

    unsigned short* hbufs[2] = {hb0, hb1};
    unsigned int* myflags = flags + (g << 9);

    for (int t = 0; t < T_STEPS; t++) {
        const unsigned short* hrd = hbufs[t & 1];
        unsigned short* hwr = hbufs[(t + 1) & 1];

        f32x4 aR[4]  = {{0,0,0,0},{0,0,0,0},{0,0,0,0},{0,0,0,0}};
        f32x4 aZ[4]  = {{0,0,0,0},{0,0,0,0},{0,0,0,0},{0,0,0,0}};
        f32x4 aIN[4] = {{0,0,0,0},{0,0,0,0},{0,0,0,0},{0,0,0,0}};
        f32x4 aHN[4] = {{0,0,0,0},{0,0,0,0},{0,0,0,0},{0,0,0,0}};

        // ---- x-part (no h dependency — overlaps the wait) ----
        const unsigned short* xrow = xt + (size_t)t * BATCH * DINP;
        #pragma unroll
        for (int xi = 0; xi < 3; xi++) {
            if (xi < nxc) {
                int kx = (w + xi * 4) * 32;
                #pragma unroll
                for (int s = 0; s < 4; s++) {
                    bf16x8 a = *(const bf16x8*)(xrow + (size_t)(bb + s * 16 + ln) * DINP + kx + q * 8);
                    aR[s]  = __builtin_amdgcn_mfma_f32_16x16x32_bf16(a, xw[xi][0], aR[s],  0, 0, 0);
                    aZ[s]  = __builtin_amdgcn_mfma_f32_16x16x32_bf16(a, xw[xi][1], aZ[s],  0, 0, 0);
                    aIN[s] = __builtin_amdgcn_mfma_f32_16x16x32_bf16(a, xw[xi][2], aIN[s], 0, 0, 0);
                }
            }
        }

        // ---- wait for h(t): all 64 blocks of this group wrote it ----
        if (t > 0) {
            if (tid == 0) {
                while (__hip_atomic_load(&myflags[t - 1], __ATOMIC_RELAXED,
                                         __HIP_MEMORY_SCOPE_AGENT) != 64u)
                    __builtin_amdgcn_s_sleep(1);
                __builtin_amdgcn_fence(__ATOMIC_ACQUIRE, "agent");
            }
        }
        __syncthreads();   // [A] release x-phase / order after acquire

        // ---- h-part: wave w does chunks c = w + 4*ci ----
        #pragma unroll
        for (int ci = 0; ci < 8; ci++) {
            int k0 = (w + ci * 4) * 32;
            bf16x8 br = *(const bf16x8*)(&wlds[(0  + ln) * W_STRIDE + k0 + q * 8]);
            bf16x8 bz = *(const bf16x8*)(&wlds[(16 + ln) * W_STRIDE + k0 + q * 8]);
            bf16x8 bn = *(const bf16x8*)(&wlds[(32 + ln) * W_STRIDE + k0 + q * 8]);
            #pragma unroll
            for (int s = 0; s < 4; s++) {
                bf16x8 a = *(const bf16x8*)(hrd + (size_t)(bb + s * 16 + ln) * HID + k0 + q * 8);
                aR[s]  = __builtin_amdgcn_mfma_f32_16x16x32_bf16(a, br, aR[s],  0, 0, 0);
                aZ[s]  = __builtin_amdgcn_mfma_f32_16x16x32_bf16(a, bz, aZ[s],  0, 0, 0);
                aHN[s] = __builtin_amdgcn_mfma_f32_16x16x32_bf16(a, bn, aHN[s], 0, 0, 0);
            }
        }

        // ---- cross-wave K-reduction: write partials for quarters we don't own ----
        #pragma unroll
        for (int s = 0; s < 4; s++) {
            if (s != w) {
                int j = w - (w > s ? 1 : 0);
                int base = (s * 3 + j) * 4;
                #pragma unroll
                for (int r = 0; r < 4; r++) {
                    int ro = (q * 4 + r) * 17 + ln;
                    buf[(base + 0) * 272 + ro] = aR[s][r];
                    buf[(base + 1) * 272 + ro] = aZ[s][r];
                    buf[(base + 2) * 272 + ro] = aIN[s][r];
                    buf[(base + 3) * 272 + ro] = aHN[s][r];
                }
            }
        }
        __syncthreads();   // [C]

        // own-quarter accs (wave-uniform selects, no dynamic reg indexing)
        f32x4 myR  = (w == 0) ? aR[0]  : (w == 1) ? aR[1]  : (w == 2) ? aR[2]  : aR[3];
        f32x4 myZ  = (w == 0) ? aZ[0]  : (w == 1) ? aZ[1]  : (w == 2) ? aZ[2]  : aZ[3];
        f32x4 myIN = (w == 0) ? aIN[0] : (w == 1) ? aIN[1] : (w == 2) ? aIN[2] : aIN[3];
        f32x4 myHN = (w == 0) ? aHN[0] : (w == 1) ? aHN[1] : (w == 2) ? aHN[2] : aHN[3];

        float R[4], Z[4], IN[4], HN[4];
        #pragma unroll
        for (int r = 0; r < 4; r++) { R[r] = myR[r]; Z[r] = myZ[r]; IN[r] = myIN[r]; HN[r] = myHN[r]; }
        #pragma unroll
        for (int j = 0; j < 3; j++) {
            int base = (w * 3 + j) * 4;
            #pragma unroll
            for (int r = 0; r < 4; r++) {
                int ro = (q * 4 + r) * 17 + ln;
                R[r]  += buf[(base + 0) * 272 + ro];
                Z[r]  += buf[(base + 1) * 272 + ro];
                IN[r] += buf[(base + 2) * 272 + ro];
                HN[r] += buf[(base + 3) * 272 + ro];
            }
        }

        // ---- gates + state update; write bf16 h(t+1) ----
        #pragma unroll
        for (int r = 0; r < 4; r++) {
            float pr = R[r] + bR;
            float pz = Z[r] + bZ;
            float rg = 1.f / (1.f + expf(-pr));
            float zg = 1.f / (1.f + expf(-pz));
            float ng = tanhf(IN[r] + bIN + rg * (HN[r] + bHN));
            float hn = (1.f - zg) * ng + zg * hreg[r];
            hreg[r] = hn;
            size_t addr = (size_t)(bb + w * 16 + q * 4 + r) * HID + gu;
            hwr[addr] = f2bf(hn);
            if (t == T_STEPS - 1) hF[addr] = hn;
        }

        __syncthreads();   // [D] drains every wave's h stores (vmcnt(0) at barrier)
        if (tid == 0)
            __hip_atomic_fetch_add(&myflags[t], 1u, __ATOMIC_RELEASE,
                                   __HIP_MEMORY_SCOPE_AGENT);
    }
}

// out[b][o] = h[b] . W_out[o] + b_out[o]
__global__ void out_proj(const float* __restrict__ h, const float* __restrict__ Wout,
                         const float* __restrict__ bout, float* __restrict__ out) {
    int b = blockIdx.x;    // 256
    int o = threadIdx.x;   // 128
    const float* hr = h + (size_t)b * HID;
    const float* wr = Wout + (size_t)o * HID;
    float s0 = 0.f, s1 = 0.f, s2 = 0.f, s3 = 0.f;
    for (int u = 0; u < HID; u += 4) {
        s0 += hr[u + 0] * wr[u + 0];
        s1 += hr[u + 1] * wr[u + 1];
        s2 += hr[u + 2] * wr[u + 2];
        s3 += hr[u + 3] * wr[u + 3];
    }
    out[b * OUTD + o] = (s0 + s1) + (s2 + s3) + bout[o];
}

extern "C" void kernel_launch(void* const* d_in, const int* in_sizes, int n_in,
                              void* d_out, int out_size, void* d_ws, size_t ws_size,
                              hipStream_t stream) {
    const float* x     = (const float*)d_in[0];
    const float* mask  = (const float*)d_in[1];
    const float* ti    = (const float*)d_in[2];
    const float* W_ih  = (const float*)d_in[3];
    const float* W_hh  = (const float*)d_in[4];
    const float* b_ih  = (const float*)d_in[5];
    const float* b_hh  = (const float*)d_in[6];
    const float* W_out = (const float*)d_in[7];
    const float* b_out = (const float*)d_in[8];
    float* out = (float*)d_out;

    char* ws = (char*)d_ws;
    unsigned int* flags = (unsigned int*)ws;                       // 4*512*4 = 8192 B
    unsigned short* hb0 = (unsigned short*)(ws + 8192);            // 512 KB
    unsigned short* hb1 = (unsigned short*)(ws + 8192 + 524288);   // 512 KB
    float* hF           = (float*)(ws + 8192 + 2 * 524288);        // 1 MB
    unsigned short* xtb = (unsigned short*)(ws + 8192 + 2 * 524288 + 1048576); // 75.5 MB

    // zero flags + h(0) (contiguous)
    (void)hipMemsetAsync(ws, 0, 8192 + 524288, stream);

    build_xt<<<4096, 256, 0, stream>>>(x, mask, ti, xtb);

    (void)hipFuncSetAttribute((const void*)gru_persist,
                              hipFuncAttributeMaxDynamicSharedMemorySize, LDS_BYTES);

    gru_persist<<<256, 256, LDS_BYTES, stream>>>(xtb, W_ih, W_hh, b_ih, b_hh,
                                                 hb0, hb1, hF, flags);

    out_proj<<<256, 128, 0, stream>>>(hF, W_out, b_out, out);
}

// Round 4
// 7356.868 us; speedup vs baseline: 1.1835x; 1.1835x over previous
//
#include <hip/hip_runtime.h>
#include <math.h>

#define T_STEPS 512
#define BATCH   256
#define DFEAT   128
#define DIN     257
#define DINP    288   // 257 padded to multiple of 32 (zeros)
#define HID     1024
#define G3      3072
#define OUTD    128

#define W_STRIDE 1032            // LDS row stride (shorts) for W_hh slice: 1024 + 8 pad
#define BUF_F32  13056           // 48 gate-blocks * 272 (16*17) f32
#define HTILE_OFF (BUF_F32 * 4 + 48 * W_STRIDE * 2)       // 52224 + 99072 = 151296
#define LDS_BYTES (HTILE_OFF + 64 * 16 * 2)               // + 2048 = 153344

typedef __bf16 bf16x8 __attribute__((ext_vector_type(8)));
typedef float  f32x4  __attribute__((ext_vector_type(4)));

__device__ __forceinline__ unsigned short f2bf(float f) {
    unsigned int u = __float_as_uint(f);
    u += 0x7FFF + ((u >> 16) & 1);   // round-to-nearest-even
    return (unsigned short)(u >> 16);
}

// Coherent (agent-scope, L1/L2-bypassing) 8B h access: h lives at the device
// coherence point (Infinity Cache), so cross-XCD visibility needs NO fences
// (no buffer_wbl2 / buffer_inv per step — that was R3's 16.8 us/step).
__device__ __forceinline__ bf16x8 load_h_frag(const unsigned long long* p) {
    union { unsigned long long u[2]; bf16x8 v; } t;
    t.u[0] = __hip_atomic_load(p,     __ATOMIC_RELAXED, __HIP_MEMORY_SCOPE_AGENT);
    t.u[1] = __hip_atomic_load(p + 1, __ATOMIC_RELAXED, __HIP_MEMORY_SCOPE_AGENT);
    return t.v;
}

// Build xt[t][b][c] (bf16, zero-padded to DINP) from x[b][t][d], mask[b][t][d], ti[b][t]
__global__ void build_xt(const float* __restrict__ x, const float* __restrict__ mask,
                         const float* __restrict__ ti, unsigned short* __restrict__ xt) {
    const int N = T_STEPS * BATCH * DINP;
    for (int idx = blockIdx.x * blockDim.x + threadIdx.x; idx < N;
         idx += gridDim.x * blockDim.x) {
        int c   = idx % DINP;
        int rem = idx / DINP;
        int b   = rem % BATCH;
        int t   = rem / BATCH;
        float v;
        if (c < DFEAT)            v = x[(b * T_STEPS + t) * DFEAT + c];
        else if (c < 2 * DFEAT)   v = mask[(b * T_STEPS + t) * DFEAT + (c - DFEAT)];
        else if (c == 2 * DFEAT)  v = ti[b * T_STEPS + t];
        else                      v = 0.f;
        xt[idx] = f2bf(v);
    }
}

// Persistent GRU: 256 blocks (1/CU), block = (unit-tile ut, batch-group g).
// W_hh slice LDS-resident all 512 steps; W_ih frags in regs; waves K-split.
// Cross-step sync: relaxed flag counters; h exchanged via coherent atomics.
__global__ __launch_bounds__(256, 1) void gru_persist(
    const unsigned short* __restrict__ xt,
    const float* __restrict__ W_ih, const float* __restrict__ W_hh,
    const float* __restrict__ b_ih, const float* __restrict__ b_hh,
    unsigned long long* hb0, unsigned long long* hb1,
    float* __restrict__ hF, unsigned int* flags)
{
    extern __shared__ char smem[];
    float* buf = (float*)smem;                                    // 52224 B
    unsigned short* wlds  = (unsigned short*)(smem + BUF_F32 * 4); // 48 x 1032 shorts
    unsigned short* htile = (unsigned short*)(smem + HTILE_OFF);   // 64 x 16 shorts

    const int tid = threadIdx.x;
    const int w   = tid >> 6;          // wave 0..3
    const int ln  = tid & 15;          // unit lane / A row lane
    const int q   = (tid & 63) >> 4;   // quad
    const int g   = blockIdx.x >> 6;   // batch group 0..3
    const int ut  = blockIdx.x & 63;   // unit tile 0..63
    const int u0  = ut * 16;
    const int bb  = g * 64;

    // ---- load W_hh slice into LDS (f32 -> bf16), rows = gate*16 + u ----
    for (int i = tid; i < 48 * 512; i += 256) {
        int row = i >> 9;                 // 0..47
        int c2  = (i & 511) * 2;          // 0..1022 step 2
        int grow = (row >> 4) * HID + u0 + (row & 15);
        const float* src = W_hh + (size_t)grow * HID + c2;
        unsigned int lo = f2bf(src[0]), hi = f2bf(src[1]);
        *(unsigned int*)(&wlds[row * W_STRIDE + c2]) = lo | (hi << 16);
    }

    // ---- W_ih fragments into registers: wave w owns x-chunks {w, w+4, w+8(<9)} ----
    bf16x8 xw[3][3];   // [chunk][gate r,z,n]
    const int nxc = (w == 0) ? 3 : 2;
    #pragma unroll
    for (int xi = 0; xi < 3; xi++) {
        int cx = w + xi * 4;
        #pragma unroll
        for (int G = 0; G < 3; G++) {
            unsigned short tmp[8];
            #pragma unroll
            for (int j = 0; j < 8; j++) {
                int col = cx * 32 + q * 8 + j;
                float f = (cx < 9 && col < DIN)
                    ? W_ih[(size_t)(G * HID + u0 + ln) * DIN + col] : 0.f;
                tmp[j] = f2bf(f);
            }
            xw[xi][G] = *(bf16x8*)tmp;
        }
    }

    // ---- biases (per lane unit), fp32 master h in regs ----
    const int gu = u0 + ln;
    const float bR  = b_ih[gu]            + b_hh[gu];
    const float bZ  = b_ih[HID + gu]      + b_hh[HID + gu];
    const float bIN = b_ih[2 * HID + gu];
    const float bHN = b_hh[2 * HID + gu];
    float hreg[4] = {0.f, 0.f, 0.f, 0.f};

    __syncthreads();

    unsigned long long* hbufs[2] = {hb0, hb1};
    unsigned int* myflags = flags + (g << 9);

    for (int t = 0; t < T_STEPS; t++) {
        const unsigned long long* hrd = hbufs[t & 1];
        unsigned long long* hwr = hbufs[(t + 1) & 1];

        f32x4 aR[4]  = {{0,0,0,0},{0,0,0,0},{0,0,0,0},{0,0,0,0}};
        f32x4 aZ[4]  = {{0,0,0,0},{0,0,0,0},{0,0,0,0},{0,0,0,0}};
        f32x4 aIN[4] = {{0,0,0,0},{0,0,0,0},{0,0,0,0},{0,0,0,0}};
        f32x4 aHN[4] = {{0,0,0,0},{0,0,0,0},{0,0,0,0},{0,0,0,0}};

        // ---- x-part (no h dependency — overlaps the wait) ----
        const unsigned short* xrow = xt + (size_t)t * BATCH * DINP;
        #pragma unroll
        for (int xi = 0; xi < 3; xi++) {
            if (xi < nxc) {
                int kx = (w + xi * 4) * 32;
                #pragma unroll
                for (int s = 0; s < 4; s++) {
                    bf16x8 a = *(const bf16x8*)(xrow + (size_t)(bb + s * 16 + ln) * DINP + kx + q * 8);
                    aR[s]  = __builtin_amdgcn_mfma_f32_16x16x32_bf16(a, xw[xi][0], aR[s],  0, 0, 0);
                    aZ[s]  = __builtin_amdgcn_mfma_f32_16x16x32_bf16(a, xw[xi][1], aZ[s],  0, 0, 0);
                    aIN[s] = __builtin_amdgcn_mfma_f32_16x16x32_bf16(a, xw[xi][2], aIN[s], 0, 0, 0);
                }
            }
        }

        // ---- wait for h(t): all 64 blocks of this group wrote it (no fence:
        //      h goes through the coherent point via atomic load/store) ----
        if (t > 0) {
            if (tid == 0) {
                while (__hip_atomic_load(&myflags[t - 1], __ATOMIC_RELAXED,
                                         __HIP_MEMORY_SCOPE_AGENT) != 64u)
                    __builtin_amdgcn_s_sleep(1);
            }
        }
        __syncthreads();   // [A]

        // ---- h-part: wave w does chunks c = w + 4*ci ----
        #pragma unroll
        for (int ci = 0; ci < 8; ci++) {
            int k0 = (w + ci * 4) * 32;
            bf16x8 br = *(const bf16x8*)(&wlds[(0  + ln) * W_STRIDE + k0 + q * 8]);
            bf16x8 bz = *(const bf16x8*)(&wlds[(16 + ln) * W_STRIDE + k0 + q * 8]);
            bf16x8 bn = *(const bf16x8*)(&wlds[(32 + ln) * W_STRIDE + k0 + q * 8]);
            #pragma unroll
            for (int s = 0; s < 4; s++) {
                bf16x8 a = load_h_frag(hrd + ((((size_t)(bb + s * 16 + ln)) * HID + k0 + q * 8) >> 2));
                aR[s]  = __builtin_amdgcn_mfma_f32_16x16x32_bf16(a, br, aR[s],  0, 0, 0);
                aZ[s]  = __builtin_amdgcn_mfma_f32_16x16x32_bf16(a, bz, aZ[s],  0, 0, 0);
                aHN[s] = __builtin_amdgcn_mfma_f32_16x16x32_bf16(a, bn, aHN[s], 0, 0, 0);
            }
        }

        // ---- cross-wave K-reduction: write partials for quarters we don't own ----
        #pragma unroll
        for (int s = 0; s < 4; s++) {
            if (s != w) {
                int j = w - (w > s ? 1 : 0);
                int base = (s * 3 + j) * 4;
                #pragma unroll
                for (int r = 0; r < 4; r++) {
                    int ro = (q * 4 + r) * 17 + ln;
                    buf[(base + 0) * 272 + ro] = aR[s][r];
                    buf[(base + 1) * 272 + ro] = aZ[s][r];
                    buf[(base + 2) * 272 + ro] = aIN[s][r];
                    buf[(base + 3) * 272 + ro] = aHN[s][r];
                }
            }
        }
        __syncthreads();   // [C]

        f32x4 myR  = (w == 0) ? aR[0]  : (w == 1) ? aR[1]  : (w == 2) ? aR[2]  : aR[3];
        f32x4 myZ  = (w == 0) ? aZ[0]  : (w == 1) ? aZ[1]  : (w == 2) ? aZ[2]  : aZ[3];
        f32x4 myIN = (w == 0) ? aIN[0] : (w == 1) ? aIN[1] : (w == 2) ? aIN[2] : aIN[3];
        f32x4 myHN = (w == 0) ? aHN[0] : (w == 1) ? aHN[1] : (w == 2) ? aHN[2] : aHN[3];

        float R[4], Z[4], IN[4], HN[4];
        #pragma unroll
        for (int r = 0; r < 4; r++) { R[r] = myR[r]; Z[r] = myZ[r]; IN[r] = myIN[r]; HN[r] = myHN[r]; }
        #pragma unroll
        for (int j = 0; j < 3; j++) {
            int base = (w * 3 + j) * 4;
            #pragma unroll
            for (int r = 0; r < 4; r++) {
                int ro = (q * 4 + r) * 17 + ln;
                R[r]  += buf[(base + 0) * 272 + ro];
                Z[r]  += buf[(base + 1) * 272 + ro];
                IN[r] += buf[(base + 2) * 272 + ro];
                HN[r] += buf[(base + 3) * 272 + ro];
            }
        }

        // ---- gates + state update; h(t+1) bf16 into LDS tile [batch][unit] ----
        #pragma unroll
        for (int r = 0; r < 4; r++) {
            float pr = R[r] + bR;
            float pz = Z[r] + bZ;
            float rg = 1.f / (1.f + expf(-pr));
            float zg = 1.f / (1.f + expf(-pz));
            float ng = tanhf(IN[r] + bIN + rg * (HN[r] + bHN));
            float hn = (1.f - zg) * ng + zg * hreg[r];
            hreg[r] = hn;
            int lb = w * 16 + q * 4 + r;              // local batch 0..63
            htile[lb * 16 + ln] = f2bf(hn);
            if (t == T_STEPS - 1) hF[(size_t)(bb + lb) * HID + gu] = hn;
        }
        __syncthreads();   // [E] htile complete

        // ---- packed coherent h store: thread i -> (batch i/4, unit-quad i%4) ----
        {
            int lb = tid >> 2;
            int ug = (tid & 3) * 4;
            unsigned long long pk = *(const unsigned long long*)(&htile[lb * 16 + ug]);
            __hip_atomic_store(hwr + ((((size_t)(bb + lb)) * HID + u0 + ug) >> 2), pk,
                               __ATOMIC_RELAXED, __HIP_MEMORY_SCOPE_AGENT);
        }

        __syncthreads();   // [D] vmcnt(0) drain: all h stores coherent-visible
        if (tid == 0)
            __hip_atomic_fetch_add(&myflags[t], 1u, __ATOMIC_RELAXED,
                                   __HIP_MEMORY_SCOPE_AGENT);
    }
}

// out[b][o] = h[b] . W_out[o] + b_out[o]
__global__ void out_proj(const float* __restrict__ h, const float* __restrict__ Wout,
                         const float* __restrict__ bout, float* __restrict__ out) {
    int b = blockIdx.x;    // 256
    int o = threadIdx.x;   // 128
    const float* hr = h + (size_t)b * HID;
    const float* wr = Wout + (size_t)o * HID;
    float s0 = 0.f, s1 = 0.f, s2 = 0.f, s3 = 0.f;
    for (int u = 0; u < HID; u += 4) {
        s0 += hr[u + 0] * wr[u + 0];
        s1 += hr[u + 1] * wr[u + 1];
        s2 += hr[u + 2] * wr[u + 2];
        s3 += hr[u + 3] * wr[u + 3];
    }
    out[b * OUTD + o] = (s0 + s1) + (s2 + s3) + bout[o];
}

extern "C" void kernel_launch(void* const* d_in, const int* in_sizes, int n_in,
                              void* d_out, int out_size, void* d_ws, size_t ws_size,
                              hipStream_t stream) {
    const float* x     = (const float*)d_in[0];
    const float* mask  = (const float*)d_in[1];
    const float* ti    = (const float*)d_in[2];
    const float* W_ih  = (const float*)d_in[3];
    const float* W_hh  = (const float*)d_in[4];
    const float* b_ih  = (const float*)d_in[5];
    const float* b_hh  = (const float*)d_in[6];
    const float* W_out = (const float*)d_in[7];
    const float* b_out = (const float*)d_in[8];
    float* out = (float*)d_out;

    char* ws = (char*)d_ws;
    unsigned int* flags     = (unsigned int*)ws;                       // 8192 B
    unsigned long long* hb0 = (unsigned long long*)(ws + 8192);        // 512 KB
    unsigned long long* hb1 = (unsigned long long*)(ws + 8192 + 524288);
    float* hF               = (float*)(ws + 8192 + 2 * 524288);        // 1 MB
    unsigned short* xtb     = (unsigned short*)(ws + 8192 + 2 * 524288 + 1048576);

    // zero flags + h(0) (contiguous)
    (void)hipMemsetAsync(ws, 0, 8192 + 524288, stream);

    build_xt<<<4096, 256, 0, stream>>>(x, mask, ti, xtb);

    (void)hipFuncSetAttribute((const void*)gru_persist,
                              hipFuncAttributeMaxDynamicSharedMemorySize, LDS_BYTES);

    gru_persist<<<256, 256, LDS_BYTES, stream>>>(xtb, W_ih, W_hh, b_ih, b_hh,
                                                 hb0, hb1, hF, flags);

    out_proj<<<256, 128, 0, stream>>>(hF, W_out, b_out, out);
}

// Round 6
// 6137.130 us; speedup vs baseline: 1.4187x; 1.1987x over previous
//
#include <hip/hip_runtime.h>
#include <math.h>

#define T_STEPS 512
#define BATCH   256
#define DFEAT   128
#define DIN     257
#define DINP    288   // 257 padded to multiple of 32 (zeros)
#define HID     1024
#define G3      3072
#define OUTD    128

#define W_STRIDE 1032            // LDS row stride (shorts) for W_hh slice: 1024 + 8 pad
#define BUF_F32  13056           // 48 gate-blocks * 272 (16*17) f32
#define HTILE_OFF (BUF_F32 * 4 + 48 * W_STRIDE * 2)       // 52224 + 99072 = 151296
#define LDS_BYTES (HTILE_OFF + 64 * 16 * 2)               // + 2048 = 153344

typedef __bf16 bf16x8 __attribute__((ext_vector_type(8)));
typedef float  f32x4  __attribute__((ext_vector_type(4)));

__device__ __forceinline__ unsigned short f2bf(float f) {
    unsigned int u = __float_as_uint(f);
    u += 0x7FFF + ((u >> 16) & 1);   // round-to-nearest-even
    return (unsigned short)(u >> 16);
}

// Coherent (agent-scope, L1/L2-bypassing) 8B h access: h lives at the device
// coherence point (Infinity Cache) — no per-step fences needed.
__device__ __forceinline__ bf16x8 load_h_frag(const unsigned long long* p) {
    union { unsigned long long u[2]; bf16x8 v; } t;
    t.u[0] = __hip_atomic_load(p,     __ATOMIC_RELAXED, __HIP_MEMORY_SCOPE_AGENT);
    t.u[1] = __hip_atomic_load(p + 1, __ATOMIC_RELAXED, __HIP_MEMORY_SCOPE_AGENT);
    return t.v;
}

// Build xt[t][b][c] (bf16, zero-padded to DINP) from x[b][t][d], mask[b][t][d], ti[b][t]
__global__ void build_xt(const float* __restrict__ x, const float* __restrict__ mask,
                         const float* __restrict__ ti, unsigned short* __restrict__ xt) {
    const int N = T_STEPS * BATCH * DINP;
    for (int idx = blockIdx.x * blockDim.x + threadIdx.x; idx < N;
         idx += gridDim.x * blockDim.x) {
        int c   = idx % DINP;
        int rem = idx / DINP;
        int b   = rem % BATCH;
        int t   = rem / BATCH;
        float v;
        if (c < DFEAT)            v = x[(b * T_STEPS + t) * DFEAT + c];
        else if (c < 2 * DFEAT)   v = mask[(b * T_STEPS + t) * DFEAT + (c - DFEAT)];
        else if (c == 2 * DFEAT)  v = ti[b * T_STEPS + t];
        else                      v = 0.f;
        xt[idx] = f2bf(v);
    }
}

// Persistent GRU: 256 blocks (1/CU), block = (unit-tile ut, batch-group g).
// W_hh slice LDS-resident all 512 steps; W_ih frags in regs; waves K-split.
// Sync: per-block slot flags (no RMW contention), 64-thread poll w/ s_sleep.
// h-part: ALL 32 fragments preloaded into regs in one burst, then MFMA.
__global__ __launch_bounds__(256, 1) void gru_persist(
    const unsigned short* __restrict__ xt,
    const float* __restrict__ W_ih, const float* __restrict__ W_hh,
    const float* __restrict__ b_ih, const float* __restrict__ b_hh,
    unsigned long long* hb0, unsigned long long* hb1,
    float* __restrict__ hF, unsigned int* flags)
{
    extern __shared__ char smem[];
    float* buf = (float*)smem;                                    // 52224 B
    unsigned short* wlds  = (unsigned short*)(smem + BUF_F32 * 4); // 48 x 1032 shorts
    unsigned short* htile = (unsigned short*)(smem + HTILE_OFF);   // 64 x 16 shorts

    const int tid = threadIdx.x;
    const int w   = tid >> 6;          // wave 0..3
    const int ln  = tid & 15;          // unit lane / A row lane
    const int q   = (tid & 63) >> 4;   // quad
    const int g   = blockIdx.x >> 6;   // batch group 0..3
    const int ut  = blockIdx.x & 63;   // unit tile 0..63
    const int u0  = ut * 16;
    const int bb  = g * 64;

    // ---- load W_hh slice into LDS (f32 -> bf16), rows = gate*16 + u ----
    for (int i = tid; i < 48 * 512; i += 256) {
        int row = i >> 9;                 // 0..47
        int c2  = (i & 511) * 2;          // 0..1022 step 2
        int grow = (row >> 4) * HID + u0 + (row & 15);
        const float* src = W_hh + (size_t)grow * HID + c2;
        unsigned int lo = f2bf(src[0]), hi = f2bf(src[1]);
        *(unsigned int*)(&wlds[row * W_STRIDE + c2]) = lo | (hi << 16);
    }

    // ---- W_ih fragments into registers: wave w owns x-chunks {w, w+4, w+8(<9)} ----
    bf16x8 xw[3][3];   // [chunk][gate r,z,n]
    const int nxc = (w == 0) ? 3 : 2;
    #pragma unroll
    for (int xi = 0; xi < 3; xi++) {
        int cx = w + xi * 4;
        #pragma unroll
        for (int G = 0; G < 3; G++) {
            unsigned short tmp[8];
            #pragma unroll
            for (int j = 0; j < 8; j++) {
                int col = cx * 32 + q * 8 + j;
                float f = (cx < 9 && col < DIN)
                    ? W_ih[(size_t)(G * HID + u0 + ln) * DIN + col] : 0.f;
                tmp[j] = f2bf(f);
            }
            xw[xi][G] = *(bf16x8*)tmp;
        }
    }

    // ---- biases (per lane unit), fp32 master h in regs ----
    const int gu = u0 + ln;
    const float bR  = b_ih[gu]            + b_hh[gu];
    const float bZ  = b_ih[HID + gu]      + b_hh[HID + gu];
    const float bIN = b_ih[2 * HID + gu];
    const float bHN = b_hh[2 * HID + gu];
    float hreg[4] = {0.f, 0.f, 0.f, 0.f};

    __syncthreads();

    unsigned long long* hbufs[2] = {hb0, hb1};

    for (int t = 0; t < T_STEPS; t++) {
        const unsigned long long* hrd = hbufs[t & 1];
        unsigned long long* hwr = hbufs[(t + 1) & 1];

        f32x4 aR[4]  = {{0,0,0,0},{0,0,0,0},{0,0,0,0},{0,0,0,0}};
        f32x4 aZ[4]  = {{0,0,0,0},{0,0,0,0},{0,0,0,0},{0,0,0,0}};
        f32x4 aIN[4] = {{0,0,0,0},{0,0,0,0},{0,0,0,0},{0,0,0,0}};
        f32x4 aHN[4] = {{0,0,0,0},{0,0,0,0},{0,0,0,0},{0,0,0,0}};

        // ---- x-part (no h dependency — overlaps producer tail) ----
        const unsigned short* xrow = xt + (size_t)t * BATCH * DINP;
        #pragma unroll
        for (int xi = 0; xi < 3; xi++) {
            if (xi < nxc) {
                int kx = (w + xi * 4) * 32;
                #pragma unroll
                for (int s = 0; s < 4; s++) {
                    bf16x8 a = *(const bf16x8*)(xrow + (size_t)(bb + s * 16 + ln) * DINP + kx + q * 8);
                    aR[s]  = __builtin_amdgcn_mfma_f32_16x16x32_bf16(a, xw[xi][0], aR[s],  0, 0, 0);
                    aZ[s]  = __builtin_amdgcn_mfma_f32_16x16x32_bf16(a, xw[xi][1], aZ[s],  0, 0, 0);
                    aIN[s] = __builtin_amdgcn_mfma_f32_16x16x32_bf16(a, xw[xi][2], aIN[s], 0, 0, 0);
                }
            }
        }

        // ---- wait for h(t): 64 per-block slots, 64-thread poll w/ backoff ----
        if (t > 0 && tid < 64) {
            const unsigned int* slot = flags + ((size_t)(t - 1) * 4 + g) * 64 + tid;
            while (__hip_atomic_load(slot, __ATOMIC_RELAXED,
                                     __HIP_MEMORY_SCOPE_AGENT) == 0u)
                __builtin_amdgcn_s_sleep(1);
        }
        __syncthreads();   // [A]

        // ---- h-part: preload ALL fragments (back-to-back, pipelined) ----
        bf16x8 hfrag[8][4];
        #pragma unroll
        for (int ci = 0; ci < 8; ci++) {
            int k0 = (w + ci * 4) * 32;
            #pragma unroll
            for (int s = 0; s < 4; s++) {
                hfrag[ci][s] = load_h_frag(
                    hrd + ((((size_t)(bb + s * 16 + ln)) * HID + k0 + q * 8) >> 2));
            }
        }
        // ---- then MFMA from registers ----
        #pragma unroll
        for (int ci = 0; ci < 8; ci++) {
            int k0 = (w + ci * 4) * 32;
            bf16x8 br = *(const bf16x8*)(&wlds[(0  + ln) * W_STRIDE + k0 + q * 8]);
            bf16x8 bz = *(const bf16x8*)(&wlds[(16 + ln) * W_STRIDE + k0 + q * 8]);
            bf16x8 bn = *(const bf16x8*)(&wlds[(32 + ln) * W_STRIDE + k0 + q * 8]);
            #pragma unroll
            for (int s = 0; s < 4; s++) {
                aR[s]  = __builtin_amdgcn_mfma_f32_16x16x32_bf16(hfrag[ci][s], br, aR[s],  0, 0, 0);
                aZ[s]  = __builtin_amdgcn_mfma_f32_16x16x32_bf16(hfrag[ci][s], bz, aZ[s],  0, 0, 0);
                aHN[s] = __builtin_amdgcn_mfma_f32_16x16x32_bf16(hfrag[ci][s], bn, aHN[s], 0, 0, 0);
            }
        }

        // ---- cross-wave K-reduction: write partials for quarters we don't own ----
        #pragma unroll
        for (int s = 0; s < 4; s++) {
            if (s != w) {
                int j = w - (w > s ? 1 : 0);
                int base = (s * 3 + j) * 4;
                #pragma unroll
                for (int r = 0; r < 4; r++) {
                    int ro = (q * 4 + r) * 17 + ln;
                    buf[(base + 0) * 272 + ro] = aR[s][r];
                    buf[(base + 1) * 272 + ro] = aZ[s][r];
                    buf[(base + 2) * 272 + ro] = aIN[s][r];
                    buf[(base + 3) * 272 + ro] = aHN[s][r];
                }
            }
        }
        __syncthreads();   // [C]

        f32x4 myR  = (w == 0) ? aR[0]  : (w == 1) ? aR[1]  : (w == 2) ? aR[2]  : aR[3];
        f32x4 myZ  = (w == 0) ? aZ[0]  : (w == 1) ? aZ[1]  : (w == 2) ? aZ[2]  : aZ[3];
        f32x4 myIN = (w == 0) ? aIN[0] : (w == 1) ? aIN[1] : (w == 2) ? aIN[2] : aIN[3];
        f32x4 myHN = (w == 0) ? aHN[0] : (w == 1) ? aHN[1] : (w == 2) ? aHN[2] : aHN[3];

        float R[4], Z[4], IN[4], HN[4];
        #pragma unroll
        for (int r = 0; r < 4; r++) { R[r] = myR[r]; Z[r] = myZ[r]; IN[r] = myIN[r]; HN[r] = myHN[r]; }
        #pragma unroll
        for (int j = 0; j < 3; j++) {
            int base = (w * 3 + j) * 4;
            #pragma unroll
            for (int r = 0; r < 4; r++) {
                int ro = (q * 4 + r) * 17 + ln;
                R[r]  += buf[(base + 0) * 272 + ro];
                Z[r]  += buf[(base + 1) * 272 + ro];
                IN[r] += buf[(base + 2) * 272 + ro];
                HN[r] += buf[(base + 3) * 272 + ro];
            }
        }

        // ---- gates + state update; h(t+1) bf16 into LDS tile [batch][unit] ----
        #pragma unroll
        for (int r = 0; r < 4; r++) {
            float pr = R[r] + bR;
            float pz = Z[r] + bZ;
            float rg = 1.f / (1.f + expf(-pr));
            float zg = 1.f / (1.f + expf(-pz));
            float ng = tanhf(IN[r] + bIN + rg * (HN[r] + bHN));
            float hn = (1.f - zg) * ng + zg * hreg[r];
            hreg[r] = hn;
            int lb = w * 16 + q * 4 + r;              // local batch 0..63
            htile[lb * 16 + ln] = f2bf(hn);
            if (t == T_STEPS - 1) hF[(size_t)(bb + lb) * HID + gu] = hn;
        }
        __syncthreads();   // [E] htile complete

        // ---- packed coherent h store: thread i -> (batch i/4, unit-quad i%4) ----
        {
            int lb = tid >> 2;
            int ug = (tid & 3) * 4;
            unsigned long long pk = *(const unsigned long long*)(&htile[lb * 16 + ug]);
            __hip_atomic_store(hwr + ((((size_t)(bb + lb)) * HID + u0 + ug) >> 2), pk,
                               __ATOMIC_RELAXED, __HIP_MEMORY_SCOPE_AGENT);
        }

        __syncthreads();   // [D] vmcnt(0) drain: all h stores coherent-visible
        if (tid == 0)
            __hip_atomic_store(flags + ((size_t)t * 4 + g) * 64 + ut, 1u,
                               __ATOMIC_RELAXED, __HIP_MEMORY_SCOPE_AGENT);
    }
}

// out[b][o] = h[b] . W_out[o] + b_out[o]
__global__ void out_proj(const float* __restrict__ h, const float* __restrict__ Wout,
                         const float* __restrict__ bout, float* __restrict__ out) {
    int b = blockIdx.x;    // 256
    int o = threadIdx.x;   // 128
    const float* hr = h + (size_t)b * HID;
    const float* wr = Wout + (size_t)o * HID;
    float s0 = 0.f, s1 = 0.f, s2 = 0.f, s3 = 0.f;
    for (int u = 0; u < HID; u += 4) {
        s0 += hr[u + 0] * wr[u + 0];
        s1 += hr[u + 1] * wr[u + 1];
        s2 += hr[u + 2] * wr[u + 2];
        s3 += hr[u + 3] * wr[u + 3];
    }
    out[b * OUTD + o] = (s0 + s1) + (s2 + s3) + bout[o];
}

extern "C" void kernel_launch(void* const* d_in, const int* in_sizes, int n_in,
                              void* d_out, int out_size, void* d_ws, size_t ws_size,
                              hipStream_t stream) {
    const float* x     = (const float*)d_in[0];
    const float* mask  = (const float*)d_in[1];
    const float* ti    = (const float*)d_in[2];
    const float* W_ih  = (const float*)d_in[3];
    const float* W_hh  = (const float*)d_in[4];
    const float* b_ih  = (const float*)d_in[5];
    const float* b_hh  = (const float*)d_in[6];
    const float* W_out = (const float*)d_in[7];
    const float* b_out = (const float*)d_in[8];
    float* out = (float*)d_out;

    char* ws = (char*)d_ws;
    unsigned int* flags     = (unsigned int*)ws;                        // 512 KB (512*4*64*4)
    unsigned long long* hb0 = (unsigned long long*)(ws + 524288);       // 512 KB
    unsigned long long* hb1 = (unsigned long long*)(ws + 2 * 524288);   // 512 KB
    float* hF               = (float*)(ws + 3 * 524288);                // 1 MB
    unsigned short* xtb     = (unsigned short*)(ws + 3 * 524288 + 1048576);

    // zero flags + h(0) (contiguous)
    (void)hipMemsetAsync(ws, 0, 2 * 524288, stream);

    build_xt<<<4096, 256, 0, stream>>>(x, mask, ti, xtb);

    (void)hipFuncSetAttribute((const void*)gru_persist,
                              hipFuncAttributeMaxDynamicSharedMemorySize, LDS_BYTES);

    gru_persist<<<256, 256, LDS_BYTES, stream>>>(xtb, W_ih, W_hh, b_ih, b_hh,
                                                 hb0, hb1, hF, flags);

    out_proj<<<256, 128, 0, stream>>>(hF, W_out, b_out, out);
}